// Round 8
// baseline (84.653 us; speedup 1.0000x reference)
//
#include <hip/hip_runtime.h>
#include <math.h>

// Problem constants (fixed by the reference's setup_inputs)
#define CLS 2
#define BATCH 8
#define HH 512
#define WW 512
#define INV_SCALE 0.125f
#define LOGEPS -16.118095651f   // log(1e-7)

#define NSTRIP 8192   // (BATCH*HH*WW)/256 strips of 256 px

// ws layout (all slots written unconditionally by main -> no zero-init needed):
//   float pf[4][NSTRIP] @ 0       (131072 B)  so0, so1, sq0, sq1 per strip
//   int   pi[2][NSTRIP] @ 131072  ( 65536 B)  po(obj cnts packed), pc(noobj cnts)

// 256 threads = 4 INDEPENDENT waves; each wave owns one 256-px row strip.
// Targets prepped inline per wave (4.5 KB array, cache-hot). No LDS, no
// __syncthreads, no atomics: partials go to unique per-strip slots.
__global__ __launch_bounds__(256) void heatmap_main(
    const float* __restrict__ predict, const float* __restrict__ targets,
    int nT, float* __restrict__ out, float* __restrict__ pf,
    int* __restrict__ pi)
{
    const int wid = threadIdx.x >> 6;
    const int l   = threadIdx.x & 63;
    const int sidx = blockIdx.x * 4 + wid;      // strip index 0..8191
    const int blockPix = sidx * 256;
    const int b  = blockPix >> 18;              // / (H*W)
    const int i  = (blockPix >> 9) & (HH - 1);  // row
    const int j0 = blockPix & (WW - 1);         // 0 or 256
    const float gy = (float)i + 0.5f;

    const int j = j0 + 4 * l;
    const float gxb = (float)j + 0.5f;

    int objm[4] = {0, 0, 0, 0}, outm[4] = {0, 0, 0, 0};

    // --- inline target prep + strip-interval filter (lane-strided) ---
    for (int base = 0; base < nT; base += 64) {
        const int t = base + l;
        float cs = 0.f, sn = 0.f, x3 = 0.f, x4 = 0.f, y3 = 0.f, y4 = 0.f;
        int cid = 0;
        bool acc = false;
        if (t < nT) {
            const float* tp = targets + t * 7;
            const int tb = (int)tp[0];
            cid = (int)tp[1];
            const float cx = tp[2] * INV_SCALE, cy = tp[3] * INV_SCALE;
            const float w_ = tp[4] * INV_SCALE, h_ = tp[5] * INV_SCALE;
            cs = cosf(tp[6]); sn = sinf(tp[6]);
            const float x = cx * cs + cy * sn;
            const float y = -cx * sn + cy * cs;
            x3 = x - 0.5f * h_; x4 = x + 0.5f * h_;
            y3 = y - 0.5f * w_; y4 = y + 0.5f * w_;
            // strip: gx in [j0+0.5, j0+255.5], gy fixed -> exact vx/vy intervals
            const float gxl = (float)j0 + 0.5f, gxh = (float)j0 + 255.5f;
            const float a1 = cs * gxl + sn * gy, a2 = cs * gxh + sn * gy;
            const float b1 = -sn * gxl + cs * gy, b2 = -sn * gxh + cs * gy;
            const float vxlo = fminf(a1, a2), vxhi = fmaxf(a1, a2);
            const float vylo = fminf(b1, b2), vyhi = fmaxf(b1, b2);
            const float M = 0.51f;  // outer margin 0.5 + fp slack
            acc = (tb == b) & (vxhi >= x3 - M) & (vxlo <= x4 + M) &
                  (vyhi >= y3 - M) & (vylo <= y4 + M);
        }
        unsigned long long bal = __ballot(acc);   // wave-uniform hit mask
        while (bal) {
            const int n = __builtin_ctzll(bal);   // uniform lane index
            bal &= bal - 1;
            const float ccs = __shfl(cs, n), csn = __shfl(sn, n);
            const float cx3 = __shfl(x3, n), cx4 = __shfl(x4, n);
            const float cy3 = __shfl(y3, n), cy4 = __shfl(y4, n);
            const int cbit = 1 << __shfl(cid, n);
            float vx = ccs * gxb + csn * gy;
            float vy = -csn * gxb + ccs * gy;
            #pragma unroll
            for (int k = 0; k < 4; ++k) {
                const bool in_  = (cx3 <= vx) & (vx <= cx4) &
                                  (cy3 <= vy) & (vy <= cy4);
                const bool out_ = (cx3 - 0.5f <= vx) & (vx <= cx4 + 0.5f) &
                                  (cy3 - 0.5f <= vy) & (vy <= cy4 + 0.5f);
                if (in_)  objm[k] |= cbit;
                if (out_) outm[k] |= cbit;
                vx += ccs; vy -= csn;
            }
        }
    }

    // --- vectorized loads; sigmoid/log algebra (5 transcendentals/px) ---
    const int pbase = (b * CLS * HH + i) * WW + j;   // 16B-aligned (j = 4l)
    const float4 P0 = *(const float4*)(predict + pbase);
    const float4 P1 = *(const float4*)(predict + pbase + HH * WW);

    float so0 = 0.f, so1 = 0.f, sq0 = 0.f, sq1 = 0.f;
    int c_obj0 = 0, c_obj1 = 0, c_no0 = 0, c_no1 = 0;
    float hm[4];
    #pragma unroll
    for (int k = 0; k < 4; ++k) {
        const float p0 = (&P0.x)[k], p1 = (&P1.x)[k];
        const float t0 = __expf(p0), t1 = __expf(p1);
        const float l0n = -__logf(1.0f + t0);       // log(1-conf0)
        const float l1n = -__logf(1.0f + t1);
        const float lc0 = fmaxf(p0 + l0n, LOGEPS);  // log(conf0), EPS-clipped
        const float lc1 = fmaxf(p1 + l1n, LOGEPS);
        const float l0c = fmaxf(l0n, LOGEPS);
        const float l1c = fmaxf(l1n, LOGEPS);
        const float tm = fmaxf(t0, t1);
        hm[k] = tm * __builtin_amdgcn_rcpf(1.0f + tm);  // sigmoid(max(p0,p1))
        const int om = objm[k], um = outm[k];
        if (om & 1) { so0 += lc0; ++c_obj0; }
        if (om & 2) { so1 += lc1; ++c_obj1; }
        if (!(um & 1)) { sq0 += l0c; ++c_no0; }
        if (!(um & 2)) { sq1 += l1c; ++c_no1; }
    }

    float* ho = out + 1 + (b * HH + i) * WW + j;  // +1: misaligned -> 4 dwords
    ho[0] = hm[0]; ho[1] = hm[1]; ho[2] = hm[2]; ho[3] = hm[3];

    // --- wave reduction; obj trees skipped wave-uniformly when empty ---
    const unsigned long long anyobj =
        __ballot((objm[0] | objm[1] | objm[2] | objm[3]) != 0);
    int pc = (c_no0 & 0xffff) | (c_no1 << 16);
    #pragma unroll
    for (int off = 32; off >= 1; off >>= 1) {
        sq0 += __shfl_down(sq0, off);
        sq1 += __shfl_down(sq1, off);
        pc  += __shfl_down(pc, off);
    }
    int po = 0;
    if (anyobj) {
        po = (c_obj0 & 0xffff) | (c_obj1 << 16);
        #pragma unroll
        for (int off = 32; off >= 1; off >>= 1) {
            so0 += __shfl_down(so0, off);
            so1 += __shfl_down(so1, off);
            po  += __shfl_down(po, off);
        }
    }
    // If anyobj==0, every lane's so0/so1/po are already 0 -> writing lane-0's
    // unreduced values is still correct. Every slot written unconditionally.
    if (l == 0) {
        pf[0 * NSTRIP + sidx] = so0;
        pf[1 * NSTRIP + sidx] = so1;
        pf[2 * NSTRIP + sidx] = sq0;
        pf[3 * NSTRIP + sidx] = sq1;
        pi[0 * NSTRIP + sidx] = po;
        pi[1 * NSTRIP + sidx] = pc;
    }
}

__global__ __launch_bounds__(1024) void heatmap_finalize(
    const float* __restrict__ pf, const int* __restrict__ pi,
    float* __restrict__ out)
{
    const int t = threadIdx.x;   // 0..1023
    double f[4] = {0, 0, 0, 0};
    int c[4] = {0, 0, 0, 0};
    for (int s = t; s < NSTRIP; s += 1024) {
        f[0] += pf[0 * NSTRIP + s];
        f[1] += pf[1 * NSTRIP + s];
        f[2] += pf[2 * NSTRIP + s];
        f[3] += pf[3 * NSTRIP + s];
        const int po = pi[0 * NSTRIP + s];
        const int pc = pi[1 * NSTRIP + s];
        c[0] += po & 0xffff; c[1] += po >> 16;
        c[2] += pc & 0xffff; c[3] += pc >> 16;
    }
    #pragma unroll
    for (int off = 32; off >= 1; off >>= 1) {
        #pragma unroll
        for (int q = 0; q < 4; ++q) {
            f[q] += __shfl_down(f[q], off);
            c[q] += __shfl_down(c[q], off);
        }
    }
    __shared__ double sf[16][4];
    __shared__ int    si[16][4];
    const int wv = t >> 6, ln = t & 63;
    if (ln == 0) {
        #pragma unroll
        for (int q = 0; q < 4; ++q) { sf[wv][q] = f[q]; si[wv][q] = c[q]; }
    }
    __syncthreads();
    if (t == 0) {
        double F[4] = {0, 0, 0, 0}; int C[4] = {0, 0, 0, 0};
        for (int w = 0; w < 16; ++w)
            #pragma unroll
            for (int q = 0; q < 4; ++q) { F[q] += sf[w][q]; C[q] += si[w][q]; }
        float loss = 0.0f;
        #pragma unroll
        for (int cls = 0; cls < CLS; ++cls) {
            const int no = C[cls];
            const int nn = C[2 + cls];
            if (no > 0) {
                const float lo  = -(float)F[cls]     / (float)(no > 1 ? no : 1);
                const float ln_ = -(float)F[2 + cls] / (float)(nn > 1 ? nn : 1);
                loss += lo + ln_;  // NO_OBJ_SCALE = 1.0
            }
        }
        out[0] = loss;
    }
}

extern "C" void kernel_launch(void* const* d_in, const int* in_sizes, int n_in,
                              void* d_out, int out_size, void* d_ws, size_t ws_size,
                              hipStream_t stream) {
    const float* predict = (const float*)d_in[0];
    const float* targets = (const float*)d_in[1];
    const int nT = in_sizes[1] / 7;
    float* out = (float*)d_out;
    char* ws = (char*)d_ws;
    float* pf = (float*)ws;
    int* pi = (int*)(ws + 4 * NSTRIP * sizeof(float));

    heatmap_main<<<NSTRIP / 4, 256, 0, stream>>>(predict, targets, nT, out,
                                                 pf, pi);
    heatmap_finalize<<<1, 1024, 0, stream>>>(pf, pi, out);
}